// Round 1
// baseline (186.602 us; speedup 1.0000x reference)
//
#include <hip/hip_runtime.h>
#include <math.h>

// NetVLAD fp32: N=32, D=512, K=64, P=1024 (32x32)
// K1: logits GEMM + softmax -> A[n][k][p], spart[n][16][k]
// K2: V = A·x^T - s*c, intra-normalize rows -> out, rq[n][k]
// K3: global L2 scale per n.

namespace {

constexpr int NI   = 32;
constexpr int DIMC = 512;
constexpr int KCL  = 64;
constexpr int PIXN = 1024;
constexpr float EPSF = 1e-12f;

// ---------------------------------------------------------------------------
// K1: 512 blocks (n=32 x 16 pixel-groups of 64), 512 threads = 8 waves.
// Wave kg owns k in [kg*8, kg*8+8); lane pg owns pixel pb+pg.
// conv_w accesses are wave-uniform -> compiler emits s_load (SGPR broadcast).
// x chunk staged transposed in LDS: xsT[p][dd], pad 68 (conflict-free b128).
// ---------------------------------------------------------------------------
__global__ __launch_bounds__(512) void k1_logits_softmax(
    const float* __restrict__ x, const float* __restrict__ conv_w,
    const float* __restrict__ conv_b, float* __restrict__ A,
    float* __restrict__ spart)
{
  __shared__ float xsT[64 * 68];
  __shared__ float red[2][8][64];
  const int tid = threadIdx.x;
  const int kg  = __builtin_amdgcn_readfirstlane(tid >> 6);  // wave id 0..7
  const int pg  = tid & 63;
  const int blk = blockIdx.x;
  const int n   = blk >> 4;
  const int pbi = blk & 15;
  const int pb  = pbi << 6;
  const int k0  = kg << 3;

  float acc[8];
#pragma unroll
  for (int i = 0; i < 8; ++i) acc[i] = 0.0f;

  const float* xn = x + (size_t)n * DIMC * PIXN + pb;

  for (int ch = 0; ch < 8; ++ch) {   // D in chunks of 64
    const int db = ch << 6;
    __syncthreads();
    // stage xsT[pp][dd] = x[n][db+dd][pb+pp]; 1024 float4, 2 per thread
#pragma unroll
    for (int it = 0; it < 2; ++it) {
      const int idx = it * 512 + tid;
      const int dd  = idx >> 4;
      const int c4  = idx & 15;
      const float4 v = *reinterpret_cast<const float4*>(
          xn + (size_t)(db + dd) * PIXN + (c4 << 2));
      const int p0 = c4 << 2;
      xsT[(p0 + 0) * 68 + dd] = v.x;
      xsT[(p0 + 1) * 68 + dd] = v.y;
      xsT[(p0 + 2) * 68 + dd] = v.z;
      xsT[(p0 + 3) * 68 + dd] = v.w;
    }
    __syncthreads();
#pragma unroll
    for (int s8 = 0; s8 < 8; ++s8) {  // 8 d's per step
      float xf[8];
      const float4 xa = *reinterpret_cast<const float4*>(&xsT[pg * 68 + s8 * 8]);
      const float4 xb = *reinterpret_cast<const float4*>(&xsT[pg * 68 + s8 * 8 + 4]);
      xf[0] = xa.x; xf[1] = xa.y; xf[2] = xa.z; xf[3] = xa.w;
      xf[4] = xb.x; xf[5] = xb.y; xf[6] = xb.z; xf[7] = xb.w;
#pragma unroll
      for (int i = 0; i < 8; ++i) {
        const float* wp = conv_w + (size_t)(k0 + i) * DIMC + db + s8 * 8;
        const float4 wa = *reinterpret_cast<const float4*>(wp);
        const float4 wb = *reinterpret_cast<const float4*>(wp + 4);
        acc[i] = fmaf(wa.x, xf[0], acc[i]);
        acc[i] = fmaf(wa.y, xf[1], acc[i]);
        acc[i] = fmaf(wa.z, xf[2], acc[i]);
        acc[i] = fmaf(wa.w, xf[3], acc[i]);
        acc[i] = fmaf(wb.x, xf[4], acc[i]);
        acc[i] = fmaf(wb.y, xf[5], acc[i]);
        acc[i] = fmaf(wb.z, xf[6], acc[i]);
        acc[i] = fmaf(wb.w, xf[7], acc[i]);
      }
    }
  }
#pragma unroll
  for (int i = 0; i < 8; ++i) acc[i] += conv_b[k0 + i];

  // softmax over all 64 k (cross-wave via LDS red arrays; fixed order ->
  // deterministic)
  float pmax = acc[0];
#pragma unroll
  for (int i = 1; i < 8; ++i) pmax = fmaxf(pmax, acc[i]);
  red[0][kg][pg] = pmax;
  __syncthreads();
  float m = red[0][0][pg];
#pragma unroll
  for (int j = 1; j < 8; ++j) m = fmaxf(m, red[0][j][pg]);
  float ps = 0.0f;
#pragma unroll
  for (int i = 0; i < 8; ++i) { acc[i] = __expf(acc[i] - m); ps += acc[i]; }
  red[1][kg][pg] = ps;
  __syncthreads();
  float S = red[1][0][pg];
#pragma unroll
  for (int j = 1; j < 8; ++j) S += red[1][j][pg];
  const float rS = 1.0f / S;

  float* Ap = A + ((size_t)n * KCL + k0) * PIXN + pb + pg;
#pragma unroll
  for (int i = 0; i < 8; ++i) {
    acc[i] *= rS;
    Ap[(size_t)i * PIXN] = acc[i];
  }
  // per-block partial column sums of a (for s = sum_p a), deterministic tree
#pragma unroll
  for (int i = 0; i < 8; ++i) {
    float v = acc[i];
#pragma unroll
    for (int off = 32; off > 0; off >>= 1) v += __shfl_xor(v, off, 64);
    if (pg == 0) spart[((size_t)n * 16 + pbi) * 64 + k0 + i] = v;
  }
}

// ---------------------------------------------------------------------------
// K2: 256 blocks (n=32 x 8 k-tiles of 8), 256 threads = 4 waves.
// Wave w owns k = kt*8 + 2w + {0,1}; lane l owns d in [8l, 8l+8).
// A accesses wave-uniform -> s_load. x chunk (16 p x 512 d) double-buffered
// in LDS [p][d] (stride 512 words -> 2-way bank alias on b128 reads = free).
// Fused: -s*c subtraction + intra (per-row) L2 normalization via wave shfl.
// ---------------------------------------------------------------------------
__global__ __launch_bounds__(256) void k2_vlad_intranorm(
    const float* __restrict__ x, const float* __restrict__ A,
    const float* __restrict__ spart, const float* __restrict__ cent,
    float* __restrict__ out, float* __restrict__ rq)
{
  __shared__ float xs[2][16 * 512];   // 64 KB, double-buffered
  const int tid = threadIdx.x;
  const int w   = __builtin_amdgcn_readfirstlane(tid >> 6);  // 0..3
  const int l   = tid & 63;
  const int blk = blockIdx.x;
  const int n   = blk >> 3;
  const int kt  = blk & 7;
  const int ka  = (kt << 3) + (w << 1);
  const int d0  = l << 3;

  const float* xn  = x + (size_t)n * DIMC * PIXN;
  const float* a0p = A + ((size_t)n * KCL + ka) * PIXN;
  const float* a1p = a0p + PIXN;

  float acc0[8], acc1[8];
#pragma unroll
  for (int j = 0; j < 8; ++j) { acc0[j] = 0.0f; acc1[j] = 0.0f; }

  float4 st[8];
  // prologue: load + write chunk 0
#pragma unroll
  for (int it = 0; it < 8; ++it) {
    const int f4 = it * 256 + tid;
    const int d  = f4 >> 2;
    const int p4 = f4 & 3;
    st[it] = *reinterpret_cast<const float4*>(xn + (size_t)d * PIXN + (p4 << 2));
  }
#pragma unroll
  for (int it = 0; it < 8; ++it) {
    const int f4 = it * 256 + tid;
    const int d  = f4 >> 2;
    const int p4 = f4 & 3;
    float* dst = &xs[0][(p4 << 2) * 512 + d];
    dst[0] = st[it].x; dst[512] = st[it].y; dst[1024] = st[it].z; dst[1536] = st[it].w;
  }

  for (int pc = 0; pc < 64; ++pc) {   // P in chunks of 16
    const int cur = pc & 1;
    __syncthreads();
    if (pc + 1 < 64) {   // issue next-chunk loads (latency hides under FMAs)
#pragma unroll
      for (int it = 0; it < 8; ++it) {
        const int f4 = it * 256 + tid;
        const int d  = f4 >> 2;
        const int p4 = f4 & 3;
        st[it] = *reinterpret_cast<const float4*>(
            xn + (size_t)d * PIXN + (pc + 1) * 16 + (p4 << 2));
      }
    }
    const float* ac0 = a0p + pc * 16;
    const float* ac1 = a1p + pc * 16;
#pragma unroll
    for (int p = 0; p < 16; ++p) {
      const float av0 = ac0[p];   // wave-uniform -> s_load
      const float av1 = ac1[p];
      const float4 xa = *reinterpret_cast<const float4*>(&xs[cur][p * 512 + d0]);
      const float4 xb = *reinterpret_cast<const float4*>(&xs[cur][p * 512 + d0 + 4]);
      acc0[0] = fmaf(av0, xa.x, acc0[0]);
      acc0[1] = fmaf(av0, xa.y, acc0[1]);
      acc0[2] = fmaf(av0, xa.z, acc0[2]);
      acc0[3] = fmaf(av0, xa.w, acc0[3]);
      acc0[4] = fmaf(av0, xb.x, acc0[4]);
      acc0[5] = fmaf(av0, xb.y, acc0[5]);
      acc0[6] = fmaf(av0, xb.z, acc0[6]);
      acc0[7] = fmaf(av0, xb.w, acc0[7]);
      acc1[0] = fmaf(av1, xa.x, acc1[0]);
      acc1[1] = fmaf(av1, xa.y, acc1[1]);
      acc1[2] = fmaf(av1, xa.z, acc1[2]);
      acc1[3] = fmaf(av1, xa.w, acc1[3]);
      acc1[4] = fmaf(av1, xb.x, acc1[4]);
      acc1[5] = fmaf(av1, xb.y, acc1[5]);
      acc1[6] = fmaf(av1, xb.z, acc1[6]);
      acc1[7] = fmaf(av1, xb.w, acc1[7]);
    }
    if (pc + 1 < 64) {
#pragma unroll
      for (int it = 0; it < 8; ++it) {
        const int f4 = it * 256 + tid;
        const int d  = f4 >> 2;
        const int p4 = f4 & 3;
        float* dst = &xs[cur ^ 1][(p4 << 2) * 512 + d];
        dst[0] = st[it].x; dst[512] = st[it].y; dst[1024] = st[it].z; dst[1536] = st[it].w;
      }
    }
  }

  // epilogue: s, subtract s*c, intra-normalize (row fully in this wave)
  float s0 = 0.0f, s1 = 0.0f;
#pragma unroll
  for (int b = 0; b < 16; ++b) {   // fixed order -> deterministic
    s0 += spart[((size_t)n * 16 + b) * 64 + ka];
    s1 += spart[((size_t)n * 16 + b) * 64 + ka + 1];
  }
  const float* c0 = cent + (size_t)ka * DIMC + d0;
  const float* c1 = c0 + DIMC;
  const float4 c0a = *reinterpret_cast<const float4*>(c0);
  const float4 c0b = *reinterpret_cast<const float4*>(c0 + 4);
  const float4 c1a = *reinterpret_cast<const float4*>(c1);
  const float4 c1b = *reinterpret_cast<const float4*>(c1 + 4);
  float r0[8], r1[8];
  r0[0] = acc0[0] - s0 * c0a.x; r0[1] = acc0[1] - s0 * c0a.y;
  r0[2] = acc0[2] - s0 * c0a.z; r0[3] = acc0[3] - s0 * c0a.w;
  r0[4] = acc0[4] - s0 * c0b.x; r0[5] = acc0[5] - s0 * c0b.y;
  r0[6] = acc0[6] - s0 * c0b.z; r0[7] = acc0[7] - s0 * c0b.w;
  r1[0] = acc1[0] - s1 * c1a.x; r1[1] = acc1[1] - s1 * c1a.y;
  r1[2] = acc1[2] - s1 * c1a.z; r1[3] = acc1[3] - s1 * c1a.w;
  r1[4] = acc1[4] - s1 * c1b.x; r1[5] = acc1[5] - s1 * c1b.y;
  r1[6] = acc1[6] - s1 * c1b.z; r1[7] = acc1[7] - s1 * c1b.w;

  float ssq0 = 0.0f, ssq1 = 0.0f;
#pragma unroll
  for (int j = 0; j < 8; ++j) { ssq0 = fmaf(r0[j], r0[j], ssq0); ssq1 = fmaf(r1[j], r1[j], ssq1); }
#pragma unroll
  for (int off = 32; off > 0; off >>= 1) {
    ssq0 += __shfl_xor(ssq0, off, 64);
    ssq1 += __shfl_xor(ssq1, off, 64);
  }
  const float inv0 = 1.0f / fmaxf(sqrtf(ssq0), EPSF);
  const float inv1 = 1.0f / fmaxf(sqrtf(ssq1), EPSF);

  float* o0 = out + ((size_t)n * KCL + ka) * DIMC + d0;
  float* o1 = o0 + DIMC;
  float4 w0a = make_float4(r0[0] * inv0, r0[1] * inv0, r0[2] * inv0, r0[3] * inv0);
  float4 w0b = make_float4(r0[4] * inv0, r0[5] * inv0, r0[6] * inv0, r0[7] * inv0);
  float4 w1a = make_float4(r1[0] * inv1, r1[1] * inv1, r1[2] * inv1, r1[3] * inv1);
  float4 w1b = make_float4(r1[4] * inv1, r1[5] * inv1, r1[6] * inv1, r1[7] * inv1);
  *reinterpret_cast<float4*>(o0)     = w0a;
  *reinterpret_cast<float4*>(o0 + 4) = w0b;
  *reinterpret_cast<float4*>(o1)     = w1a;
  *reinterpret_cast<float4*>(o1 + 4) = w1b;
  if (l == 0) {
    rq[(size_t)n * KCL + ka]     = ssq0 * inv0 * inv0;
    rq[(size_t)n * KCL + ka + 1] = ssq1 * inv1 * inv1;
  }
}

// ---------------------------------------------------------------------------
// K3: per-n global L2 scale. 32 blocks x 256 threads.
// ---------------------------------------------------------------------------
__global__ __launch_bounds__(256) void k3_globalnorm(
    const float* __restrict__ rq, float* __restrict__ out)
{
  const int n = blockIdx.x;
  float g = 0.0f;
#pragma unroll
  for (int k = 0; k < KCL; ++k) g += rq[(size_t)n * KCL + k];  // fixed order
  const float scale = 1.0f / fmaxf(sqrtf(g), EPSF);
  float* o = out + (size_t)n * (KCL * DIMC);
  for (int i = threadIdx.x * 4; i < KCL * DIMC; i += 256 * 4) {
    float4 v = *reinterpret_cast<float4*>(o + i);
    v.x *= scale; v.y *= scale; v.z *= scale; v.w *= scale;
    *reinterpret_cast<float4*>(o + i) = v;
  }
}

}  // namespace

extern "C" void kernel_launch(void* const* d_in, const int* in_sizes, int n_in,
                              void* d_out, int out_size, void* d_ws, size_t ws_size,
                              hipStream_t stream) {
  (void)in_sizes; (void)n_in; (void)out_size; (void)ws_size;
  const float* x      = (const float*)d_in[0];
  const float* cent   = (const float*)d_in[1];
  const float* conv_w = (const float*)d_in[2];
  const float* conv_b = (const float*)d_in[3];
  float* out = (float*)d_out;
  float* ws  = (float*)d_ws;

  // ws layout (floats): A [32][64][1024] | spart [32][16][64] | rq [32][64]
  float* A     = ws;
  float* spart = ws + (size_t)NI * KCL * PIXN;          // +2097152
  float* rq    = spart + (size_t)NI * 16 * KCL;         // +32768

  k1_logits_softmax<<<512, 512, 0, stream>>>(x, conv_w, conv_b, A, spart);
  k2_vlad_intranorm<<<256, 256, 0, stream>>>(x, A, spart, cent, out, rq);
  k3_globalnorm<<<32, 256, 0, stream>>>(rq, out);
}

// Round 2
// 137.717 us; speedup vs baseline: 1.3550x; 1.3550x over previous
//
#include <hip/hip_runtime.h>
#include <math.h>

// NetVLAD fp32: N=32, D=512, K=64, P=1024 (32x32)
// K0: W_T[d][k] = conv_w[k][d]  (one-time transpose, 128 KB)
// K1: logits GEMM (k wave-uniform via s_load of W_T rows; lanes = pixels;
//     x chunk linear in LDS via global_load_lds) + softmax -> A_T[n][p][k],
//     spart[n][16][k]
// K2a: V[n][k][d-tile] = sum_p A_T[n][p][k]*x[n][d][p] - s*c  (k wave-uniform
//     via s_load of A_T rows; lanes = d, conflict-free b32 LDS reads) ->
//     raw V into d_out + per-(n,k,dt) partial ssq
// K2b: intra + global L2 normalization, in-place scale of d_out.

namespace {

constexpr int NI   = 32;
constexpr int DIMC = 512;
constexpr int KCL  = 64;
constexpr int PIXN = 1024;
constexpr float EPSF = 1e-12f;

#define AS1 __attribute__((address_space(1)))
#define AS3 __attribute__((address_space(3)))

__device__ __forceinline__ void glds16(const float* g, float* l) {
  __builtin_amdgcn_global_load_lds((const AS1 void*)g, (AS3 void*)l, 16, 0, 0);
}

// ---------------------------------------------------------------------------
__global__ __launch_bounds__(256) void k0_wt(const float* __restrict__ w,
                                             float* __restrict__ wt) {
  const int i = blockIdx.x * 256 + threadIdx.x;   // 32768 total
  const int d = i >> 6, k = i & 63;
  wt[i] = w[(size_t)k * DIMC + d];
}

// ---------------------------------------------------------------------------
// K1: 512 blocks = (n=32 x 16 p-groups of 64), 512 threads = 8 waves.
// Wave kg owns k0 = 8*kg (uniform); lane l = pixel pb+l.
// Per d-step: 1 uniform 32B load of W_T[d][k0..k0+8] (s_load) +
// 1 ds_read_b32 x[d][l] (lane-consecutive, conflict-free) + 8 v_fma.
// x chunk [64d][64p] staged linearly via global_load_lds (lds off = tid*16B).
// ---------------------------------------------------------------------------
__global__ __launch_bounds__(512) void k1_logits(
    const float* __restrict__ x, const float* __restrict__ wt,
    const float* __restrict__ conv_b, float* __restrict__ At,
    float* __restrict__ spart)
{
  __shared__ float xs[2][4096];     // [buf][dd*64 + p], 32 KB
  __shared__ float red[2][8][64];
  const int tid = threadIdx.x;
  const int kg  = __builtin_amdgcn_readfirstlane(tid >> 6);  // 0..7
  const int l   = tid & 63;
  const int k0  = kg << 3;
  const int bid = blockIdx.x;
  // XCD swizzle: all blocks of one n land on XCD n%8 (shared with K2a).
  const int xcd = bid & 7, idx = bid >> 3;
  const int n   = xcd + ((idx & 3) << 3);
  const int pg  = idx >> 2;          // 0..15
  const int pb  = pg << 6;

  const float* xn = x + (size_t)n * DIMC * PIXN + pb;

  // prologue: issue chunk 0 (2 x 16B per thread, LDS linear = tid*16B)
  {
    const int i0 = tid, i1 = 512 + tid;
    glds16(xn + (size_t)(i0 >> 4) * PIXN + ((i0 & 15) << 2), &xs[0][i0 << 2]);
    glds16(xn + (size_t)(i1 >> 4) * PIXN + ((i1 & 15) << 2), &xs[0][i1 << 2]);
  }

  float acc[8];
#pragma unroll
  for (int i = 0; i < 8; ++i) acc[i] = 0.0f;

  for (int ch = 0; ch < 8; ++ch) {   // D in chunks of 64
    const int cur = ch & 1;
    if (ch < 7) {
      const float* xc = xn + (size_t)(ch + 1) * 64 * PIXN;
      const int i0 = tid, i1 = 512 + tid;
      glds16(xc + (size_t)(i0 >> 4) * PIXN + ((i0 & 15) << 2), &xs[cur ^ 1][i0 << 2]);
      glds16(xc + (size_t)(i1 >> 4) * PIXN + ((i1 & 15) << 2), &xs[cur ^ 1][i1 << 2]);
      asm volatile("s_waitcnt vmcnt(2)" ::: "memory");  // chunk ch done, next in flight
    } else {
      asm volatile("s_waitcnt vmcnt(0)" ::: "memory");
    }
    __builtin_amdgcn_s_barrier();
    const float* wrow = wt + ((size_t)ch * 64) * KCL + k0;   // uniform -> s_load
#pragma unroll 8
    for (int dd = 0; dd < 64; ++dd) {
      const float4 wa = *reinterpret_cast<const float4*>(wrow + dd * KCL);
      const float4 wb = *reinterpret_cast<const float4*>(wrow + dd * KCL + 4);
      const float xv = xs[cur][(dd << 6) + l];
      acc[0] = fmaf(wa.x, xv, acc[0]);
      acc[1] = fmaf(wa.y, xv, acc[1]);
      acc[2] = fmaf(wa.z, xv, acc[2]);
      acc[3] = fmaf(wa.w, xv, acc[3]);
      acc[4] = fmaf(wb.x, xv, acc[4]);
      acc[5] = fmaf(wb.y, xv, acc[5]);
      acc[6] = fmaf(wb.z, xv, acc[6]);
      acc[7] = fmaf(wb.w, xv, acc[7]);
    }
    __builtin_amdgcn_s_barrier();    // all waves done reading buf[cur]
  }

#pragma unroll
  for (int i = 0; i < 8; ++i) acc[i] += conv_b[k0 + i];

  // softmax over 64 k (cross-wave via LDS, fixed order -> deterministic)
  float pmax = acc[0];
#pragma unroll
  for (int i = 1; i < 8; ++i) pmax = fmaxf(pmax, acc[i]);
  red[0][kg][l] = pmax;
  __syncthreads();
  float m = red[0][0][l];
#pragma unroll
  for (int j = 1; j < 8; ++j) m = fmaxf(m, red[0][j][l]);
  float ps = 0.0f;
#pragma unroll
  for (int i = 0; i < 8; ++i) { acc[i] = __expf(acc[i] - m); ps += acc[i]; }
  red[1][kg][l] = ps;
  __syncthreads();
  float S = red[1][0][l];
#pragma unroll
  for (int j = 1; j < 8; ++j) S += red[1][j][l];
  const float rS = 1.0f / S;
#pragma unroll
  for (int i = 0; i < 8; ++i) acc[i] *= rS;

  // A_T[n][p][k]: per lane 32 B contiguous
  float* ap = At + ((size_t)n * PIXN + pb + l) * KCL + k0;
  *reinterpret_cast<float4*>(ap)     = make_float4(acc[0], acc[1], acc[2], acc[3]);
  *reinterpret_cast<float4*>(ap + 4) = make_float4(acc[4], acc[5], acc[6], acc[7]);

  // spart: per-block column sums (lanes = pixels), deterministic butterfly
#pragma unroll
  for (int i = 0; i < 8; ++i) {
    float v = acc[i];
#pragma unroll
    for (int off = 32; off > 0; off >>= 1) v += __shfl_xor(v, off, 64);
    if (l == 0) spart[((size_t)n * 16 + pg) * KCL + k0 + i] = v;
  }
}

// ---------------------------------------------------------------------------
// K2a: 256 blocks = (n=32 x 8 d-tiles of 64), 512 threads = 8 waves.
// Wave kg owns k0 = 8*kg (uniform); lane l = d-offset within tile.
// Per p-step: 1 uniform 32B load of A_T[n][p][k0..k0+8] (s_load) +
// 1 ds_read_b32 x[p][l] (conflict-free, pad 65) + 8 v_fma.
// x chunk [64p][64d] transposed into LDS by reg-staging (conflict-free:
// write addr = (p)*65 + dd, banks (p+dd)&31 hit each bank exactly twice).
// Epilogue: -s*c, raw V -> d_out, per-(k,dt) partial ssq -> ssqp.
// ---------------------------------------------------------------------------
__global__ __launch_bounds__(512) void k2a_vlad(
    const float* __restrict__ x, const float* __restrict__ At,
    const float* __restrict__ spart, const float* __restrict__ cent,
    float* __restrict__ out, float* __restrict__ ssqp)
{
  __shared__ float xs[2][64 * 65];   // [buf][p*65 + d], 33.3 KB
  const int tid = threadIdx.x;
  const int kg  = __builtin_amdgcn_readfirstlane(tid >> 6);
  const int l   = tid & 63;
  const int k0  = kg << 3;
  const int bid = blockIdx.x;
  const int xcd = bid & 7, idx = bid >> 3;
  const int n   = xcd + ((idx & 3) << 3);   // same n->XCD map as K1
  const int dt  = idx >> 2;                 // 0..7
  const int d0  = dt << 6;

  // staging role: thread owns row dd = tid>>3, 8 consecutive p at (tid&7)*8
  const int sdd = tid >> 3;
  const int sp0 = (tid & 7) << 3;
  const float* gx = x + ((size_t)n * DIMC + d0 + sdd) * PIXN + sp0;

  float4 st0, st1;
  st0 = *reinterpret_cast<const float4*>(gx);
  st1 = *reinterpret_cast<const float4*>(gx + 4);
  {
    float* wb = &xs[0][0];
    wb[(sp0 + 0) * 65 + sdd] = st0.x;
    wb[(sp0 + 1) * 65 + sdd] = st0.y;
    wb[(sp0 + 2) * 65 + sdd] = st0.z;
    wb[(sp0 + 3) * 65 + sdd] = st0.w;
    wb[(sp0 + 4) * 65 + sdd] = st1.x;
    wb[(sp0 + 5) * 65 + sdd] = st1.y;
    wb[(sp0 + 6) * 65 + sdd] = st1.z;
    wb[(sp0 + 7) * 65 + sdd] = st1.w;
  }

  float acc[8];
#pragma unroll
  for (int i = 0; i < 8; ++i) acc[i] = 0.0f;

  const float* an = At + (size_t)n * PIXN * KCL + k0;

  for (int ch = 0; ch < 16; ++ch) {   // P in chunks of 64
    __syncthreads();                  // chunk ch writes visible
    if (ch < 15) {                    // issue next-chunk loads early (T14)
      const float* g2 = gx + (ch + 1) * 64;
      st0 = *reinterpret_cast<const float4*>(g2);
      st1 = *reinterpret_cast<const float4*>(g2 + 4);
    }
    const float* ap = an + (size_t)ch * 64 * KCL;   // uniform -> s_load
    const float* xr = &xs[ch & 1][0];
#pragma unroll 4
    for (int p = 0; p < 64; ++p) {
      const float4 a0 = *reinterpret_cast<const float4*>(ap + p * KCL);
      const float4 a1 = *reinterpret_cast<const float4*>(ap + p * KCL + 4);
      const float xv = xr[p * 65 + l];
      acc[0] = fmaf(a0.x, xv, acc[0]);
      acc[1] = fmaf(a0.y, xv, acc[1]);
      acc[2] = fmaf(a0.z, xv, acc[2]);
      acc[3] = fmaf(a0.w, xv, acc[3]);
      acc[4] = fmaf(a1.x, xv, acc[4]);
      acc[5] = fmaf(a1.y, xv, acc[5]);
      acc[6] = fmaf(a1.z, xv, acc[6]);
      acc[7] = fmaf(a1.w, xv, acc[7]);
    }
    __syncthreads();                  // all done reading buf[ch&1]
    if (ch < 15) {
      float* wb = &xs[(ch + 1) & 1][0];
      wb[(sp0 + 0) * 65 + sdd] = st0.x;
      wb[(sp0 + 1) * 65 + sdd] = st0.y;
      wb[(sp0 + 2) * 65 + sdd] = st0.z;
      wb[(sp0 + 3) * 65 + sdd] = st0.w;
      wb[(sp0 + 4) * 65 + sdd] = st1.x;
      wb[(sp0 + 5) * 65 + sdd] = st1.y;
      wb[(sp0 + 6) * 65 + sdd] = st1.z;
      wb[(sp0 + 7) * 65 + sdd] = st1.w;
    }
  }

  // epilogue: s (fixed order), -s*c, raw V to d_out, partial ssq
  float sv[8];
#pragma unroll
  for (int i = 0; i < 8; ++i) {
    float s = 0.0f;
#pragma unroll
    for (int pt = 0; pt < 16; ++pt)
      s += spart[((size_t)n * 16 + pt) * KCL + k0 + i];
    sv[i] = s;
  }
#pragma unroll
  for (int i = 0; i < 8; ++i) {
    const float cv = cent[(size_t)(k0 + i) * DIMC + d0 + l];
    const float r = acc[i] - sv[i] * cv;
    out[((size_t)n * KCL + k0 + i) * DIMC + d0 + l] = r;
    float q = r * r;
#pragma unroll
    for (int off = 32; off > 0; off >>= 1) q += __shfl_xor(q, off, 64);
    if (l == 0) ssqp[((size_t)n * KCL + k0 + i) * 8 + dt] = q;
  }
}

// ---------------------------------------------------------------------------
// K2b: 256 blocks = (n x 8 k-chunks of 8), 256 threads.
// Wave 0 computes per-k inv + global scale (deterministic butterfly);
// all threads scale 16 floats of d_out in place.
// ---------------------------------------------------------------------------
__global__ __launch_bounds__(256) void k2b_norm(
    const float* __restrict__ ssqp, float* __restrict__ out)
{
  __shared__ float invs[64];
  __shared__ float gsh;
  const int tid = threadIdx.x;
  const int n  = blockIdx.x >> 3;
  const int kc = blockIdx.x & 7;
  if (tid < 64) {
    float ssq = 0.0f;
#pragma unroll
    for (int dt = 0; dt < 8; ++dt) ssq += ssqp[((size_t)n * KCL + tid) * 8 + dt];
    const float inv = 1.0f / fmaxf(sqrtf(ssq), EPSF);
    invs[tid] = inv;
    float rqv = ssq * inv * inv;
#pragma unroll
    for (int off = 32; off > 0; off >>= 1) rqv += __shfl_xor(rqv, off, 64);
    if (tid == 0) gsh = 1.0f / fmaxf(sqrtf(rqv), EPSF);
  }
  __syncthreads();
  const float sc = invs[(kc << 3) + (tid >> 5)] * gsh;
  float* o = out + ((size_t)n * KCL + (kc << 3)) * DIMC + tid * 16;
#pragma unroll
  for (int j = 0; j < 4; ++j) {
    float4 v = *reinterpret_cast<float4*>(o + j * 4);
    v.x *= sc; v.y *= sc; v.z *= sc; v.w *= sc;
    *reinterpret_cast<float4*>(o + j * 4) = v;
  }
}

}  // namespace

extern "C" void kernel_launch(void* const* d_in, const int* in_sizes, int n_in,
                              void* d_out, int out_size, void* d_ws, size_t ws_size,
                              hipStream_t stream) {
  (void)in_sizes; (void)n_in; (void)out_size; (void)ws_size;
  const float* x      = (const float*)d_in[0];
  const float* cent   = (const float*)d_in[1];
  const float* conv_w = (const float*)d_in[2];
  const float* conv_b = (const float*)d_in[3];
  float* out = (float*)d_out;
  float* ws  = (float*)d_ws;

  // ws layout (floats): W_T 32768 | A_T 2097152 | spart 32768 | ssqp 16384
  float* wt    = ws;
  float* At    = wt + 32768;
  float* spart = At + (size_t)NI * PIXN * KCL;
  float* ssqp  = spart + (size_t)NI * 16 * KCL;

  k0_wt    <<<128, 256, 0, stream>>>(conv_w, wt);
  k1_logits<<<512, 512, 0, stream>>>(x, wt, conv_b, At, spart);
  k2a_vlad <<<256, 512, 0, stream>>>(x, At, spart, cent, out, ssqp);
  k2b_norm <<<256, 256, 0, stream>>>(ssqp, out);
}

// Round 3
// 107.403 us; speedup vs baseline: 1.7374x; 1.2822x over previous
//
#include <hip/hip_runtime.h>
#include <math.h>

// NetVLAD fp32: N=32, D=512, K=64, P=1024 (32x32)
// K0:  W_T[d][k] = conv_w[k][d]
// K1:  logits GEMM + softmax -> A_T[n][p][k], spart[n][16][k]
//      (x AND W_T chunks double-buffered in LDS via global_load_lds;
//       per d-step: 2 broadcast ds_read_b128 (W) + 1 ds_read_b32 (x) + 8 fma)
// K2a: V = A·x^T - s*c (raw) -> d_out, partial ssq -> ssqp
//      (A_T chunks via global_load_lds; x chunks reg-staged transposed;
//       per p-step: 1 broadcast ds_read_b128 (A) + 1 ds_read_b64 (x) + 8 fma)
// K2b: intra + global L2 normalization, in-place scale of d_out.

namespace {

constexpr int NI   = 32;
constexpr int DIMC = 512;
constexpr int KCL  = 64;
constexpr int PIXN = 1024;
constexpr float EPSF = 1e-12f;

#define AS1 __attribute__((address_space(1)))
#define AS3 __attribute__((address_space(3)))

__device__ __forceinline__ void glds16(const float* g, float* l) {
  __builtin_amdgcn_global_load_lds((const AS1 void*)g, (AS3 void*)l, 16, 0, 0);
}

// ---------------------------------------------------------------------------
__global__ __launch_bounds__(256) void k0_wt(const float* __restrict__ w,
                                             float* __restrict__ wt) {
  const int i = blockIdx.x * 256 + threadIdx.x;   // 32768 total
  const int d = i >> 6, k = i & 63;
  wt[i] = w[(size_t)k * DIMC + d];
}

// ---------------------------------------------------------------------------
// K1: 512 blocks = (n=32 x 16 p-groups of 64), 512 threads = 8 waves.
// Wave kg owns k0 = 8*kg; lane l = pixel pb+l.
// ---------------------------------------------------------------------------
__global__ __launch_bounds__(512) void k1_logits(
    const float* __restrict__ x, const float* __restrict__ wt,
    const float* __restrict__ conv_b, float* __restrict__ At,
    float* __restrict__ spart)
{
  __shared__ float xs[2][4096];     // [buf][dd*64 + p]
  __shared__ float wl[2][4096];     // [buf][dd*64 + k]
  __shared__ float red[2][8][64];
  const int tid = threadIdx.x;
  const int kg  = __builtin_amdgcn_readfirstlane(tid >> 6);
  const int l   = tid & 63;
  const int k0  = kg << 3;
  const int bid = blockIdx.x;
  const int xcd = bid & 7, idx = bid >> 3;
  const int n   = xcd + ((idx & 3) << 3);   // n -> XCD n%8 (shared with K2a)
  const int pg  = idx >> 2;                 // 0..15
  const int pb  = pg << 6;

  const float* xn = x + (size_t)n * DIMC * PIXN + pb;
  const int i0 = tid, i1 = tid + 512;

  // prologue: chunk 0 (x: 64d x 64p, W: 64d x 64k), 4 glds in flight
  glds16(xn + (size_t)(i0 >> 4) * PIXN + ((i0 & 15) << 2), &xs[0][i0 << 2]);
  glds16(xn + (size_t)(i1 >> 4) * PIXN + ((i1 & 15) << 2), &xs[0][i1 << 2]);
  glds16(wt + (i0 << 2), &wl[0][i0 << 2]);
  glds16(wt + (i1 << 2), &wl[0][i1 << 2]);

  float acc[8];
#pragma unroll
  for (int i = 0; i < 8; ++i) acc[i] = 0.0f;

  for (int ch = 0; ch < 8; ++ch) {   // D in chunks of 64
    const int cur = ch & 1;
    if (ch < 7) {
      const float* xc = xn + (size_t)(ch + 1) * 64 * PIXN;
      const float* wc = wt + (ch + 1) * 4096;
      glds16(xc + (size_t)(i0 >> 4) * PIXN + ((i0 & 15) << 2), &xs[cur ^ 1][i0 << 2]);
      glds16(xc + (size_t)(i1 >> 4) * PIXN + ((i1 & 15) << 2), &xs[cur ^ 1][i1 << 2]);
      glds16(wc + (i0 << 2), &wl[cur ^ 1][i0 << 2]);
      glds16(wc + (i1 << 2), &wl[cur ^ 1][i1 << 2]);
      asm volatile("s_waitcnt vmcnt(4)" ::: "memory");   // chunk ch landed
    } else {
      asm volatile("s_waitcnt vmcnt(0)" ::: "memory");
    }
    __builtin_amdgcn_s_barrier();
    const float* wr = &wl[cur][k0];   // uniform per wave -> broadcast b128
    const float* xr = &xs[cur][l];
#pragma unroll 8
    for (int dd = 0; dd < 64; ++dd) {
      const float4 wa = *reinterpret_cast<const float4*>(wr + (dd << 6));
      const float4 wb = *reinterpret_cast<const float4*>(wr + (dd << 6) + 4);
      const float xv = xr[dd << 6];
      acc[0] = fmaf(wa.x, xv, acc[0]);
      acc[1] = fmaf(wa.y, xv, acc[1]);
      acc[2] = fmaf(wa.z, xv, acc[2]);
      acc[3] = fmaf(wa.w, xv, acc[3]);
      acc[4] = fmaf(wb.x, xv, acc[4]);
      acc[5] = fmaf(wb.y, xv, acc[5]);
      acc[6] = fmaf(wb.z, xv, acc[6]);
      acc[7] = fmaf(wb.w, xv, acc[7]);
    }
    asm volatile("" ::: "memory");
    __builtin_amdgcn_s_barrier();    // all waves done reading buf[cur]
  }

  {
    const float4 ba = *reinterpret_cast<const float4*>(conv_b + k0);
    const float4 bb = *reinterpret_cast<const float4*>(conv_b + k0 + 4);
    acc[0] += ba.x; acc[1] += ba.y; acc[2] += ba.z; acc[3] += ba.w;
    acc[4] += bb.x; acc[5] += bb.y; acc[6] += bb.z; acc[7] += bb.w;
  }

  // softmax over 64 k (cross-wave via LDS, fixed order -> deterministic)
  float pmax = acc[0];
#pragma unroll
  for (int i = 1; i < 8; ++i) pmax = fmaxf(pmax, acc[i]);
  red[0][kg][l] = pmax;
  __syncthreads();
  float m = red[0][0][l];
#pragma unroll
  for (int j = 1; j < 8; ++j) m = fmaxf(m, red[0][j][l]);
  float ps = 0.0f;
#pragma unroll
  for (int i = 0; i < 8; ++i) { acc[i] = __expf(acc[i] - m); ps += acc[i]; }
  red[1][kg][l] = ps;
  __syncthreads();
  float S = red[1][0][l];
#pragma unroll
  for (int j = 1; j < 8; ++j) S += red[1][j][l];
  const float rS = 1.0f / S;
#pragma unroll
  for (int i = 0; i < 8; ++i) acc[i] *= rS;

  // A_T[n][p][k]: per lane 32 B contiguous
  float* ap = At + ((size_t)n * PIXN + pb + l) * KCL + k0;
  *reinterpret_cast<float4*>(ap)     = make_float4(acc[0], acc[1], acc[2], acc[3]);
  *reinterpret_cast<float4*>(ap + 4) = make_float4(acc[4], acc[5], acc[6], acc[7]);

  // spart: per-block column sums (lanes = pixels), deterministic butterfly
#pragma unroll
  for (int i = 0; i < 8; ++i) {
    float v = acc[i];
#pragma unroll
    for (int off = 32; off > 0; off >>= 1) v += __shfl_xor(v, off, 64);
    if (l == 0) spart[((size_t)n * 16 + pg) * KCL + k0 + i] = v;
  }
}

// ---------------------------------------------------------------------------
// K2a: 256 blocks = (n=32 x 8 d-tiles of 64), 512 threads = 8 waves.
// Wave kg: k0 = 8*kg; lane: kh = l>>5, dl = l&31 -> k = k0+4*kh+j, d = d0+2*dl+{0,1}.
// A chunk [64p][64k] in LDS via glds (linear); x chunk [64p][64d] reg-staged
// transposed, row stride 66 (b64-aligned, conflict-free reads).
// ---------------------------------------------------------------------------
__global__ __launch_bounds__(512) void k2a_vlad(
    const float* __restrict__ x, const float* __restrict__ At,
    const float* __restrict__ spart, const float* __restrict__ cent,
    float* __restrict__ out, float* __restrict__ ssqp)
{
  __shared__ float asmem[2][4096];    // [buf][p*64 + k], 16 KB each
  __shared__ float xsp[2][64 * 66];   // [buf][p*66 + d], 16.5 KB each
  const int tid = threadIdx.x;
  const int kg  = __builtin_amdgcn_readfirstlane(tid >> 6);
  const int l   = tid & 63;
  const int k0  = kg << 3;
  const int kh  = l >> 5, dl = l & 31;
  const int bid = blockIdx.x;
  const int xcd = bid & 7, idx = bid >> 3;
  const int n   = xcd + ((idx & 3) << 3);
  const int dt  = idx >> 2;           // 0..7
  const int d0  = dt << 6;

  const float* an = At + (size_t)n * (PIXN * KCL);
  const float* xg = x + ((size_t)n * DIMC + d0) * PIXN;
  const int ia = tid, ib = tid + 512;
  const int dda = ia >> 4, ppa = (ia & 15) << 2;
  const int ddb = ib >> 4, ppb = (ib & 15) << 2;

  // prologue: chunk 0
  glds16(an + (ia << 2), &asmem[0][ia << 2]);
  glds16(an + (ib << 2), &asmem[0][ib << 2]);
  float4 sa = *reinterpret_cast<const float4*>(xg + (size_t)dda * PIXN + ppa);
  float4 sb = *reinterpret_cast<const float4*>(xg + (size_t)ddb * PIXN + ppb);
  {
    float* wbuf = &xsp[0][0];
    wbuf[(ppa + 0) * 66 + dda] = sa.x;
    wbuf[(ppa + 1) * 66 + dda] = sa.y;
    wbuf[(ppa + 2) * 66 + dda] = sa.z;
    wbuf[(ppa + 3) * 66 + dda] = sa.w;
    wbuf[(ppb + 0) * 66 + ddb] = sb.x;
    wbuf[(ppb + 1) * 66 + ddb] = sb.y;
    wbuf[(ppb + 2) * 66 + ddb] = sb.z;
    wbuf[(ppb + 3) * 66 + ddb] = sb.w;
  }
  asm volatile("s_waitcnt vmcnt(0) lgkmcnt(0)" ::: "memory");
  __builtin_amdgcn_s_barrier();

  float acc[8];
#pragma unroll
  for (int i = 0; i < 8; ++i) acc[i] = 0.0f;

  for (int ch = 0; ch < 16; ++ch) {   // P in chunks of 64
    const int cur = ch & 1;
    if (ch < 15) {                    // prefetch chunk ch+1 (overlaps compute)
      const float* an2 = an + (ch + 1) * 4096;
      glds16(an2 + (ia << 2), &asmem[cur ^ 1][ia << 2]);
      glds16(an2 + (ib << 2), &asmem[cur ^ 1][ib << 2]);
      const float* xg2 = xg + (ch + 1) * 64;
      sa = *reinterpret_cast<const float4*>(xg2 + (size_t)dda * PIXN + ppa);
      sb = *reinterpret_cast<const float4*>(xg2 + (size_t)ddb * PIXN + ppb);
    }
    const float* ar = &asmem[cur][k0 + (kh << 2)];   // uniform per half-wave
    const float* xr = &xsp[cur][dl << 1];
#pragma unroll 4
    for (int p = 0; p < 64; ++p) {
      const float4 af = *reinterpret_cast<const float4*>(ar + (p << 6));
      const float2 xv = *reinterpret_cast<const float2*>(xr + p * 66);
      acc[0] = fmaf(af.x, xv.x, acc[0]);
      acc[1] = fmaf(af.x, xv.y, acc[1]);
      acc[2] = fmaf(af.y, xv.x, acc[2]);
      acc[3] = fmaf(af.y, xv.y, acc[3]);
      acc[4] = fmaf(af.z, xv.x, acc[4]);
      acc[5] = fmaf(af.z, xv.y, acc[5]);
      acc[6] = fmaf(af.w, xv.x, acc[6]);
      acc[7] = fmaf(af.w, xv.y, acc[7]);
    }
    if (ch < 15) {
      float* wbuf = &xsp[cur ^ 1][0];
      wbuf[(ppa + 0) * 66 + dda] = sa.x;
      wbuf[(ppa + 1) * 66 + dda] = sa.y;
      wbuf[(ppa + 2) * 66 + dda] = sa.z;
      wbuf[(ppa + 3) * 66 + dda] = sa.w;
      wbuf[(ppb + 0) * 66 + ddb] = sb.x;
      wbuf[(ppb + 1) * 66 + ddb] = sb.y;
      wbuf[(ppb + 2) * 66 + ddb] = sb.z;
      wbuf[(ppb + 3) * 66 + ddb] = sb.w;
      asm volatile("s_waitcnt vmcnt(0) lgkmcnt(0)" ::: "memory");
      __builtin_amdgcn_s_barrier();
    }
  }

  // epilogue: s (fixed order), -s*c, raw V -> d_out, partial ssq
  float sv[4] = {0.0f, 0.0f, 0.0f, 0.0f};
  {
    const float* sp0 = spart + (size_t)n * 16 * KCL + k0 + (kh << 2);
#pragma unroll
    for (int pt = 0; pt < 16; ++pt) {
      const float4 spv = *reinterpret_cast<const float4*>(sp0 + pt * KCL);
      sv[0] += spv.x; sv[1] += spv.y; sv[2] += spv.z; sv[3] += spv.w;
    }
  }
  const int kbase = k0 + (kh << 2);
  const int dd2 = d0 + (dl << 1);
#pragma unroll
  for (int j = 0; j < 4; ++j) {
    const int k = kbase + j;
    const float2 cv = *reinterpret_cast<const float2*>(cent + (size_t)k * DIMC + dd2);
    const float rx = acc[2 * j]     - sv[j] * cv.x;
    const float ry = acc[2 * j + 1] - sv[j] * cv.y;
    float* op = out + ((size_t)n * KCL + k) * DIMC + dd2;
    *reinterpret_cast<float2*>(op) = make_float2(rx, ry);
    float q = fmaf(rx, rx, ry * ry);
#pragma unroll
    for (int off = 16; off > 0; off >>= 1) q += __shfl_xor(q, off, 64);
    if (dl == 0) ssqp[((size_t)n * KCL + k) * 8 + dt] = q;
  }
}

// ---------------------------------------------------------------------------
// K2b: 256 blocks = (n x 8 k-chunks of 8), 256 threads.
// ---------------------------------------------------------------------------
__global__ __launch_bounds__(256) void k2b_norm(
    const float* __restrict__ ssqp, float* __restrict__ out)
{
  __shared__ float invs[64];
  __shared__ float gsh;
  const int tid = threadIdx.x;
  const int n  = blockIdx.x >> 3;
  const int kc = blockIdx.x & 7;
  if (tid < 64) {
    float ssq = 0.0f;
#pragma unroll
    for (int dt = 0; dt < 8; ++dt) ssq += ssqp[((size_t)n * KCL + tid) * 8 + dt];
    const float inv = 1.0f / fmaxf(sqrtf(ssq), EPSF);
    invs[tid] = inv;
    float rqv = ssq * inv * inv;
#pragma unroll
    for (int off = 32; off > 0; off >>= 1) rqv += __shfl_xor(rqv, off, 64);
    if (tid == 0) gsh = 1.0f / fmaxf(sqrtf(rqv), EPSF);
  }
  __syncthreads();
  const float sc = invs[(kc << 3) + (tid >> 5)] * gsh;
  float* o = out + ((size_t)n * KCL + (kc << 3)) * DIMC + tid * 16;
#pragma unroll
  for (int j = 0; j < 4; ++j) {
    float4 v = *reinterpret_cast<float4*>(o + j * 4);
    v.x *= sc; v.y *= sc; v.z *= sc; v.w *= sc;
    *reinterpret_cast<float4*>(o + j * 4) = v;
  }
}

}  // namespace

extern "C" void kernel_launch(void* const* d_in, const int* in_sizes, int n_in,
                              void* d_out, int out_size, void* d_ws, size_t ws_size,
                              hipStream_t stream) {
  (void)in_sizes; (void)n_in; (void)out_size; (void)ws_size;
  const float* x      = (const float*)d_in[0];
  const float* cent   = (const float*)d_in[1];
  const float* conv_w = (const float*)d_in[2];
  const float* conv_b = (const float*)d_in[3];
  float* out = (float*)d_out;
  float* ws  = (float*)d_ws;

  // ws layout (floats): W_T 32768 | A_T 2097152 | spart 32768 | ssqp 16384
  float* wt    = ws;
  float* At    = wt + 32768;
  float* spart = At + (size_t)NI * PIXN * KCL;
  float* ssqp  = spart + (size_t)NI * 16 * KCL;

  k0_wt    <<<128, 256, 0, stream>>>(conv_w, wt);
  k1_logits<<<512, 512, 0, stream>>>(x, wt, conv_b, At, spart);
  k2a_vlad <<<256, 512, 0, stream>>>(x, At, spart, cent, out, ssqp);
  k2b_norm <<<256, 256, 0, stream>>>(ssqp, out);
}